// Round 1
// baseline (343.805 us; speedup 1.0000x reference)
//
#include <hip/hip_runtime.h>
#include <hip/hip_bf16.h>

typedef unsigned short u16;
typedef unsigned int   u32;
typedef __bf16 bf16_t;
typedef bf16_t bf16x8 __attribute__((ext_vector_type(8)));
typedef u16    u16x8  __attribute__((ext_vector_type(8)));
typedef float  f32x4  __attribute__((ext_vector_type(4)));

#define DIM  2048
#define SEQ  2048
#define BATCH 2
#define NH   32
#define NKVH 8
#define HD   64
#define KVDIM (NKVH*HD)   // 512
#define NQKV (DIM + 2*KVDIM)  // 3072
#define SCALE 0.125f

__device__ __forceinline__ float b2f(u16 u) {
  union { u32 i; float f; } v; v.i = ((u32)u) << 16; return v.f;
}
__device__ __forceinline__ u16 f2b(float f) {
  union { float f; u32 i; } v; v.f = f;
  u32 x = v.i;
  return (u16)((x + 0x7fffu + ((x >> 16) & 1u)) >> 16);  // RNE
}
__device__ __forceinline__ u32 pkbf2(float a, float b) {  // low=a, high=b
  __hip_bfloat162 h = __float22bfloat162_rn(float2{a, b});
  union { __hip_bfloat162 h; u32 u; } v; v.h = h; return v.u;
}
__device__ __forceinline__ int probe_bf16(const u32* probe) { return probe[0] != 0u; }
__device__ __forceinline__ float ext_ld(const void* p, long idx, int mode_bf16) {
  return mode_bf16 ? b2f(((const u16*)p)[idx]) : ((const float*)p)[idx];
}
__device__ __forceinline__ void gload_lds16(const u16* g, u16* l) {
  __builtin_amdgcn_global_load_lds((const __attribute__((address_space(1))) void*)g,
                                   (__attribute__((address_space(3))) void*)l, 16, 0, 0);
}

// ---------------- cast x (ext dtype) -> bf16, 8 elems/thread
// bf16 input: no copy needed (gemm_qkv8 reads x directly); early-exit.
__global__ void cast_x(const void* __restrict__ in, u16* __restrict__ out,
                       const u32* __restrict__ probe) {
  int mode = probe_bf16(probe);
  if (mode) return;
  long base = ((long)blockIdx.x * 256 + threadIdx.x) * 8;
  float4 f0 = *(const float4*)((const float*)in + base);
  float4 f1 = *(const float4*)((const float*)in + base + 4);
  u16x8 t;
  t[0] = f2b(f0.x); t[1] = f2b(f0.y); t[2] = f2b(f0.z); t[3] = f2b(f0.w);
  t[4] = f2b(f1.x); t[5] = f2b(f1.y); t[6] = f2b(f1.z); t[7] = f2b(f1.w);
  *(u16x8*)&out[base] = t;
}

// ---------------- fused Wq/Wk/Wv transpose into WqkvT[3072][2048]
__global__ void transpose_qkv(const void* __restrict__ Wq, const void* __restrict__ Wk,
                              const void* __restrict__ Wv, u16* __restrict__ out,
                              const u32* __restrict__ probe) {
  int mode = probe_bf16(probe);
  __shared__ u16 t[32][33];
  int xt = blockIdx.x;
  const void* in; int C, c0, obase;
  if (xt < 64)      { in = Wq; C = DIM;   c0 = xt * 32;        obase = 0; }
  else if (xt < 80) { in = Wk; C = KVDIM; c0 = (xt - 64) * 32; obase = DIM; }
  else              { in = Wv; C = KVDIM; c0 = (xt - 80) * 32; obase = DIM + KVDIM; }
  int r0 = blockIdx.y * 32;
  int tx = threadIdx.x, ty = threadIdx.y;   // (32,8)
#pragma unroll
  for (int i = 0; i < 32; i += 8)
    t[ty + i][tx] = mode ? ((const u16*)in)[(long)(r0 + ty + i) * C + c0 + tx]
                         : f2b(((const float*)in)[(long)(r0 + ty + i) * C + c0 + tx]);
  __syncthreads();
#pragma unroll
  for (int i = 0; i < 32; i += 8)
    out[(long)(obase + c0 + ty + i) * DIM + r0 + tx] = t[tx][ty + i];
}

// ---------------- Wo transpose
__global__ void transpose_w(const void* __restrict__ in, u16* __restrict__ out,
                            int R, int C, const u32* __restrict__ probe) {
  int mode = probe_bf16(probe);
  __shared__ u16 t[32][33];
  int c0 = blockIdx.x * 32, r0 = blockIdx.y * 32;
  int tx = threadIdx.x, ty = threadIdx.y;
#pragma unroll
  for (int i = 0; i < 32; i += 8)
    t[ty + i][tx] = mode ? ((const u16*)in)[(long)(r0 + ty + i) * C + c0 + tx]
                         : f2b(((const float*)in)[(long)(r0 + ty + i) * C + c0 + tx]);
  __syncthreads();
#pragma unroll
  for (int i = 0; i < 32; i += 8)
    out[(long)(c0 + ty + i) * R + r0 + tx] = t[tx][ty + i];
}

// ---------------- RoPE on Q and K in one launch; Q additionally scaled by 1/8
__global__ void rope_both(u16* __restrict__ Qb, u16* __restrict__ Kb,
                          const void* __restrict__ cosb, const void* __restrict__ sinb,
                          const u32* __restrict__ probe) {
  int mode = probe_bf16(probe);
  long gid = (long)blockIdx.x * 256 + threadIdx.x;
  const long NQp = (long)BATCH * SEQ * NH * 32;   // Q pair-slots
  u16* base_p; int n_heads; long t; float osc;
  if (gid < NQp) { base_p = Qb; n_heads = NH; t = gid; osc = SCALE; }
  else           { base_p = Kb; n_heads = NKVH; t = gid - NQp; osc = 1.0f; }
  int pair = t & 31;
  long t2 = t >> 5;
  int h = (int)(t2 % n_heads);
  long row = t2 / n_heads;
  int s = (int)(row & (SEQ - 1));
  long base = row * (n_heads * HD) + h * HD + pair;
  float q0 = b2f(base_p[base]), q1 = b2f(base_p[base + 32]);
  float c0 = ext_ld(cosb, (long)s * HD + pair, mode);
  float c1 = ext_ld(cosb, (long)s * HD + pair + 32, mode);
  float s0 = ext_ld(sinb, (long)s * HD + pair, mode);
  float s1 = ext_ld(sinb, (long)s * HD + pair + 32, mode);
  base_p[base]      = f2b((q0 * c0 - q1 * s0) * osc);
  base_p[base + 32] = f2b((q1 * c1 + q0 * s1) * osc);
}

// =====================================================================
// 8-phase counted-vmcnt GEMM core (T2+T3+T4+T5), BN=256, BK=64, K=2048.
// 8 waves (2M x 4N), wave tile WM x 64. Double-buffered K-tiles (buf0=even,
// buf1=odd tile -> all LDS addressing static). Per iteration i: compute
// tiles 2i (ph1-4) and 2i+1 (ph5-8), one C-quadrant per phase over K=64.
// Stage slots (1 unit = one A-half or B-half of a K-tile, 16B/lane loads):
//   ph1: A2(2i+1)->buf1   ph2: A1(2i+2)->buf0   ph3: B1(2i+2)->buf0
//   ph4: B2(2i+2)->buf0   ph5: A2(2i+2)->buf0   ph6: A1(2i+3)->buf1
//   ph7: B1(2i+3)->buf1   ph8: B2(2i+3)->buf1
// WAR safety: each stage targets a region whose previous reads were
// published by an earlier phase's post-read barrier (verified per slot).
// RAW safety: s_waitcnt vmcnt(N) before the barrier preceding each phase's
// ds_reads; N = loads issued after the needed unit (uniform issue rate):
//   A-gated phases: N = 6+3*AL;  B-gated: N = 4+4*AL  (AL = A-loads/unit).
// vmcnt NEVER drains to 0 in the loop. ph4/ph8: no reads, no barriers.
// Last iteration clamps stage tiles to 31 (writes land only in dead or
// identical-value regions -> benign).
// =====================================================================

#define WAITV(N) asm volatile("s_waitcnt vmcnt(%0)" :: "n"(N) : "memory")
#define WAITL()  asm volatile("s_waitcnt lgkmcnt(0)" ::: "memory")
#define BARR()   __builtin_amdgcn_s_barrier()
#define SCHEDB() __builtin_amdgcn_sched_barrier(0)
#define PRIO1()  __builtin_amdgcn_s_setprio(1)
#define PRIO0()  __builtin_amdgcn_s_setprio(0)

#define STAGE_A(h, bufi, kt) do { _Pragma("unroll") \
  for (int _j = 0; _j < AL; ++_j) \
    gload_lds16(Ax + aSrcOff[h][_j] + (kt) * 64, (u16*)&As[(bufi) * (BM * 64) + aDst[h][_j]]); } while (0)

#define STAGE_B(h, bufi, kt) do { _Pragma("unroll") \
  for (int _j = 0; _j < 2; ++_j) \
    gload_lds16(Bt + bSrcOff[h][_j] + (kt) * 64, (u16*)&Bs[(bufi) * (256 * 64) + bDst[h][_j]]); } while (0)

#define LDA_HALF(Lp, mh) do { _Pragma("unroll") \
  for (int _m = 0; _m < MH2; ++_m) { \
    const u16* _r = (Lp) + (wm * WM + (mh) * (WM / 2) + _m * 16 + l16) * 64; \
    af[_m][0] = *(const bf16x8*)&_r[sw0]; \
    af[_m][1] = *(const bf16x8*)&_r[sw1]; } } while (0)

#define LDB_HALF(Lp, nh) do { _Pragma("unroll") \
  for (int _n = 0; _n < 2; ++_n) { \
    const u16* _r = (Lp) + (wn * 64 + (nh) * 32 + _n * 16 + l16) * 64; \
    bfr[nh][_n][0] = *(const bf16x8*)&_r[sw0]; \
    bfr[nh][_n][1] = *(const bf16x8*)&_r[sw1]; } } while (0)

#define MFMA_Q(mh, nh) do { _Pragma("unroll") \
  for (int _m = 0; _m < MH2; ++_m) \
    _Pragma("unroll") \
    for (int _n = 0; _n < 2; ++_n) { \
      f32x4 _z = acc[(mh) * MH2 + _m][(nh) * 2 + _n]; \
      _z = __builtin_amdgcn_mfma_f32_16x16x32_bf16(af[_m][0], bfr[nh][_n][0], _z, 0, 0, 0); \
      _z = __builtin_amdgcn_mfma_f32_16x16x32_bf16(af[_m][1], bfr[nh][_n][1], _z, 0, 0, 0); \
      acc[(mh) * MH2 + _m][(nh) * 2 + _n] = _z; } } while (0)

template<int BM, int EPI>
__device__ __forceinline__ void gemm8_core(const u16* __restrict__ Ax, const u16* __restrict__ Bt,
                                           u16* __restrict__ Qb, u16* __restrict__ Kb,
                                           u16* __restrict__ Vt, void* __restrict__ Cout,
                                           const u32* __restrict__ probe) {
  constexpr int WM  = BM / 2;       // wave M extent (128 or 64)
  constexpr int MI  = WM / 16;      // m-frags per wave (8 or 4)
  constexpr int MH2 = MI / 2;       // m-frags per quadrant
  constexpr int AL  = BM / 128;     // A loads per unit per thread (2 or 1)
  constexpr int VM_A = 6 + 3 * AL;  // vmcnt for A-gated phases (12 / 9)
  constexpr int VM_B = 4 + 4 * AL;  // vmcnt for B-gated phases (12 / 8)
  constexpr int K = DIM;
  __shared__ __align__(16) u16 As[2 * BM * 64];
  __shared__ __align__(16) u16 Bs[2 * 256 * 64];

  int tid = threadIdx.x, lane = tid & 63, wv = tid >> 6;
  int l16 = lane & 15, q = lane >> 4;
  int wm = wv >> 2, wn = wv & 3;
  int bm0 = blockIdx.y * BM, bn0 = blockIdx.x * 256;

  // staging: lane writes 16B at LDS group_base + lane*16B (linear dest);
  // source column pre-swizzled so LDS(row, physblk) holds logical block
  // physblk ^ (row&7).
  int srow = lane >> 3;
  int scolb = ((lane & 7) ^ srow) * 8;
  int e7 = l16 & 7;
  int sw0 = (q ^ e7) * 8, sw1 = ((4 + q) ^ e7) * 8;   // read swizzle, kk=0/1

  int aSrcOff[2][AL], aDst[2][AL];
#pragma unroll
  for (int h = 0; h < 2; ++h)
#pragma unroll
    for (int j = 0; j < AL; ++j) {
      int g = wv * AL + j;
      int rb = (BM == 256) ? ((g >> 3) * 128 + h * 64 + (g & 7) * 8)
                           : ((g >> 2) * 64 + h * 32 + (g & 3) * 8);
      aSrcOff[h][j] = (bm0 + rb + srow) * K + scolb;
      aDst[h][j] = rb * 64 + lane * 8;
    }
  int bSrcOff[2][2], bDst[2][2];
#pragma unroll
  for (int h = 0; h < 2; ++h)
#pragma unroll
    for (int j = 0; j < 2; ++j) {
      int g = wv * 2 + j;
      int rb = (g >> 2) * 64 + h * 32 + (g & 3) * 8;
      bSrcOff[h][j] = (bn0 + rb + srow) * K + scolb;
      bDst[h][j] = rb * 64 + lane * 8;
    }

  const u16* As0 = As;  const u16* As1 = As + BM * 64;
  const u16* Bs0 = Bs;  const u16* Bs1 = Bs + 256 * 64;

  f32x4 acc[MI][4] = {};
  bf16x8 af[MH2][2];
  bf16x8 bfr[2][2][2];

  // prologue: iter "-1" slots ph2..ph8 in steady-state order
  STAGE_A(0, 0, 0);   // A1(0)
  STAGE_B(0, 0, 0);   // B1(0)
  STAGE_B(1, 0, 0);   // B2(0)
  STAGE_A(1, 0, 0);   // A2(0)
  STAGE_A(0, 1, 1);   // A1(1)
  STAGE_B(0, 1, 1);   // B1(1)
  STAGE_B(1, 1, 1);   // B2(1)

#pragma unroll 1
  for (int i = 0; i < 16; ++i) {
    int te = 2 * i + 2; if (te > 31) te = 31;
    int to = 2 * i + 3; if (to > 31) to = 31;
    // ---- ph1: quadrant (0,0) of even tile
    SCHEDB();
    STAGE_A(1, 1, 2 * i + 1);
    WAITV(VM_A); BARR(); SCHEDB();
    LDA_HALF(As0, 0); LDB_HALF(Bs0, 0);
    WAITL(); BARR();
    PRIO1(); MFMA_Q(0, 0); PRIO0();
    // ---- ph2: quadrant (0,1)
    SCHEDB();
    STAGE_A(0, 0, te);
    WAITV(VM_B); BARR(); SCHEDB();
    LDB_HALF(Bs0, 1);
    WAITL(); BARR();
    PRIO1(); MFMA_Q(0, 1); PRIO0();
    // ---- ph3: quadrant (1,0)
    SCHEDB();
    STAGE_B(0, 0, te);
    WAITV(VM_A); BARR(); SCHEDB();
    LDA_HALF(As0, 1);
    WAITL(); BARR();
    PRIO1(); MFMA_Q(1, 0); PRIO0();
    // ---- ph4: quadrant (1,1) — register-only, no barriers
    SCHEDB();
    STAGE_B(1, 0, te);
    PRIO1(); MFMA_Q(1, 1); PRIO0();
    // ---- ph5: quadrant (0,0) of odd tile
    SCHEDB();
    STAGE_A(1, 0, te);
    WAITV(VM_A); BARR(); SCHEDB();
    LDA_HALF(As1, 0); LDB_HALF(Bs1, 0);
    WAITL(); BARR();
    PRIO1(); MFMA_Q(0, 0); PRIO0();
    // ---- ph6: quadrant (0,1)
    SCHEDB();
    STAGE_A(0, 1, to);
    WAITV(VM_B); BARR(); SCHEDB();
    LDB_HALF(Bs1, 1);
    WAITL(); BARR();
    PRIO1(); MFMA_Q(0, 1); PRIO0();
    // ---- ph7: quadrant (1,0)
    SCHEDB();
    STAGE_B(0, 1, to);
    WAITV(VM_A); BARR(); SCHEDB();
    LDA_HALF(As1, 1);
    WAITL(); BARR();
    PRIO1(); MFMA_Q(1, 0); PRIO0();
    // ---- ph8: quadrant (1,1)
    SCHEDB();
    STAGE_B(1, 1, to);
    PRIO1(); MFMA_Q(1, 1); PRIO0();
  }

  // ---------------- epilogue
  if constexpr (EPI == 0) {   // fused QKV: split Q / K / V(transposed)
    if (bn0 < DIM) {
#pragma unroll
      for (int mi = 0; mi < MI; ++mi)
#pragma unroll
        for (int ni = 0; ni < 4; ++ni)
#pragma unroll
          for (int r = 0; r < 4; ++r) {
            int m = bm0 + wm * WM + mi * 16 + q * 4 + r;
            int n = bn0 + wn * 64 + ni * 16 + l16;
            Qb[(long)m * DIM + n] = f2b(acc[mi][ni][r]);
          }
    } else if (bn0 < DIM + KVDIM) {
#pragma unroll
      for (int mi = 0; mi < MI; ++mi)
#pragma unroll
        for (int ni = 0; ni < 4; ++ni)
#pragma unroll
          for (int r = 0; r < 4; ++r) {
            int m = bm0 + wm * WM + mi * 16 + q * 4 + r;
            int n = bn0 - DIM + wn * 64 + ni * 16 + l16;
            Kb[(long)m * KVDIM + n] = f2b(acc[mi][ni][r]);
          }
    } else {
#pragma unroll
      for (int mi = 0; mi < MI; ++mi)
#pragma unroll
        for (int ni = 0; ni < 4; ++ni) {
          int vcol = bn0 - (DIM + KVDIM) + wn * 64 + ni * 16 + l16;
          int kvh2 = vcol >> 6, d = vcol & 63;
          int m0 = bm0 + wm * WM + mi * 16 + q * 4;
          int bb = m0 >> 11, s = m0 & (SEQ - 1);
          uint2 w;
          w.x = pkbf2(acc[mi][ni][0], acc[mi][ni][1]);
          w.y = pkbf2(acc[mi][ni][2], acc[mi][ni][3]);
          *(uint2*)&Vt[((long)(bb * NKVH + kvh2) * HD + d) * SEQ + s] = w;
        }
    }
  } else {                    // output projection -> ext dtype
    int mode = probe_bf16(probe);
#pragma unroll
    for (int mi = 0; mi < MI; ++mi)
#pragma unroll
      for (int ni = 0; ni < 4; ++ni)
#pragma unroll
        for (int r = 0; r < 4; ++r) {
          int m = bm0 + wm * WM + mi * 16 + q * 4 + r;
          int n = bn0 + wn * 64 + ni * 16 + l16;
          long idx = (long)m * DIM + n;
          if (mode) ((u16*)Cout)[idx] = f2b(acc[mi][ni][r]);
          else      ((float*)Cout)[idx] = acc[mi][ni][r];
        }
  }
}

__global__ __launch_bounds__(512, 2)
void gemm_qkv8(const void* __restrict__ x, const u16* __restrict__ xb,
               const u16* __restrict__ Bt, u16* __restrict__ Qb, u16* __restrict__ Kb,
               u16* __restrict__ Vt, const u32* __restrict__ probe) {
  const u16* Ax = probe_bf16(probe) ? (const u16*)x : xb;
  gemm8_core<256, 0>(Ax, Bt, Qb, Kb, Vt, nullptr, probe);
}

__global__ __launch_bounds__(512, 2)
void gemm_ao8(const u16* __restrict__ A, const u16* __restrict__ Bt,
              void* __restrict__ C, const u32* __restrict__ probe) {
  gemm8_core<128, 1>(A, Bt, nullptr, nullptr, nullptr, C, probe);
}

// ======== fallback 128x128 fused QKV GEMM (fp32 input without xb room) ========
__launch_bounds__(256)
__global__ void gemm_qkv(const void* __restrict__ A, const u16* __restrict__ Bt,
                         u16* __restrict__ Qb, u16* __restrict__ Kb, u16* __restrict__ Vt,
                         int a_half, const u32* __restrict__ probe) {
  int mode = a_half || probe_bf16(probe);
  __shared__ __align__(16) u16 As[128 * 32];
  __shared__ __align__(16) u16 Bs[128 * 32];
  int tid = threadIdx.x, lane = tid & 63, wv = tid >> 6;
  int l16 = lane & 15, q = lane >> 4;
  int bm0 = blockIdx.y * 128, bn0 = blockIdx.x * 128;
  int mbase = (wv & 1) * 64, nbase = (wv >> 1) * 64;
  int c0 = tid, c1 = tid + 256;
  int r0 = c0 >> 2, s0 = (c0 & 3) ^ ((r0 >> 1) & 3);
  int r1 = c1 >> 2, s1 = (c1 & 3) ^ ((r1 >> 1) & 3);
  const int K = DIM;
  long aoff0 = (long)(bm0 + r0) * K + s0 * 8;
  long aoff1 = (long)(bm0 + r1) * K + s1 * 8;
  long boff0 = (long)(bn0 + r0) * K + s0 * 8;
  long boff1 = (long)(bn0 + r1) * K + s1 * 8;
  int rsw = (q ^ ((l16 >> 1) & 3)) * 8;
  f32x4 acc[4][4] = {};
  for (int k0 = 0; k0 < K; k0 += 32) {
    __syncthreads();
    if (mode) {
      gload_lds16((const u16*)A + aoff0 + k0, &As[wv * 512]);
      gload_lds16((const u16*)A + aoff1 + k0, &As[2048 + wv * 512]);
    } else {
      const float* Af = (const float*)A;
      float4 f0 = *(const float4*)(Af + aoff0 + k0);
      float4 f1 = *(const float4*)(Af + aoff0 + k0 + 4);
      u16x8 t;
      t[0] = f2b(f0.x); t[1] = f2b(f0.y); t[2] = f2b(f0.z); t[3] = f2b(f0.w);
      t[4] = f2b(f1.x); t[5] = f2b(f1.y); t[6] = f2b(f1.z); t[7] = f2b(f1.w);
      *(u16x8*)&As[c0 * 8] = t;
      float4 g0 = *(const float4*)(Af + aoff1 + k0);
      float4 g1 = *(const float4*)(Af + aoff1 + k0 + 4);
      u16x8 u;
      u[0] = f2b(g0.x); u[1] = f2b(g0.y); u[2] = f2b(g0.z); u[3] = f2b(g0.w);
      u[4] = f2b(g1.x); u[5] = f2b(g1.y); u[6] = f2b(g1.z); u[7] = f2b(g1.w);
      *(u16x8*)&As[c1 * 8] = u;
    }
    gload_lds16(Bt + boff0 + k0, &Bs[wv * 512]);
    gload_lds16(Bt + boff1 + k0, &Bs[2048 + wv * 512]);
    __syncthreads();
    bf16x8 af[4], bfr[4];
#pragma unroll
    for (int mi = 0; mi < 4; mi++)
      af[mi] = *(const bf16x8*)&As[(mbase + mi * 16 + l16) * 32 + rsw];
#pragma unroll
    for (int ni = 0; ni < 4; ni++)
      bfr[ni] = *(const bf16x8*)&Bs[(nbase + ni * 16 + l16) * 32 + rsw];
#pragma unroll
    for (int mi = 0; mi < 4; mi++)
#pragma unroll
      for (int ni = 0; ni < 4; ni++)
        acc[mi][ni] = __builtin_amdgcn_mfma_f32_16x16x32_bf16(
            af[mi], bfr[ni], acc[mi][ni], 0, 0, 0);
  }
  if (bn0 < DIM + KVDIM) {   // Q or K block
    u16* Cb; int ldc, ncol0;
    if (bn0 < DIM) { Cb = Qb; ldc = DIM; ncol0 = bn0; }
    else           { Cb = Kb; ldc = KVDIM; ncol0 = bn0 - DIM; }
#pragma unroll
    for (int mi = 0; mi < 4; mi++)
#pragma unroll
      for (int ni = 0; ni < 4; ni++)
#pragma unroll
        for (int r = 0; r < 4; r++) {
          int m = bm0 + mbase + mi * 16 + q * 4 + r;
          int n = ncol0 + nbase + ni * 16 + l16;
          Cb[(long)m * ldc + n] = f2b(acc[mi][ni][r]);
        }
  } else {                   // V block: transposed into Vt(B,KVH,64,S)
    int vcol0 = bn0 - DIM - KVDIM;
#pragma unroll
    for (int mi = 0; mi < 4; mi++)
#pragma unroll
      for (int ni = 0; ni < 4; ni++) {
        int vcol = vcol0 + nbase + ni * 16 + l16;
        int kvh2 = vcol >> 6, d = vcol & 63;
        int m = bm0 + mbase + mi * 16 + q * 4;
        int bb = m >> 11, s = m & (SEQ - 1);
        uint2 w;
        w.x = pkbf2(acc[mi][ni][0], acc[mi][ni][1]);
        w.y = pkbf2(acc[mi][ni][2], acc[mi][ni][3]);
        *(uint2*)&Vt[((long)(bb * NKVH + kvh2) * HD + d) * SEQ + s] = w;
      }
  }
}

// ---------------- fused causal attention: LDS-staged K/V, S^T, fixed-m softmax
// grid (16, B*NH), diagonal pair {i, 31-i}; block owns 64 q-rows (wave = 16).
__launch_bounds__(256, 4)
__global__ void attn_kernel(const u16* __restrict__ Q, const u16* __restrict__ K,
                            const u16* __restrict__ Vt, u16* __restrict__ AO) {
  __shared__ __align__(16) u16 Ks[64 * 64];      // [kv][d] swizzled, 8 KB
  __shared__ __align__(16) u16 Vs[64 * 64];      // [d][kv] swizzled, 8 KB
  __shared__ __align__(16) u16 Ps[4][16 * 64];   // per-wave P, swizzled, 8 KB
  int tid = threadIdx.x, lane = tid & 63, wv = tid >> 6;
  int l16 = lane & 15, q = lane >> 4;
  int i = blockIdx.x;
  int bh = blockIdx.y;
  int b = bh >> 5, h = bh & 31, kvh = h >> 2;
  const u16* Kp = K + (long)b * SEQ * KVDIM + kvh * HD;
  const u16* Vp = Vt + (long)(b * NKVH + kvh) * HD * SEQ;

  int cA = tid, cB = tid + 256;
  int rA = cA >> 3, bA = (cA & 7) ^ (rA & 7);
  int rB = cB >> 3, bB = (cB & 7) ^ (rB & 7);
  const u16* kSrcA = Kp + (long)rA * KVDIM + bA * 8;
  const u16* kSrcB = Kp + (long)rB * KVDIM + bB * 8;
  const u16* vSrcA = Vp + (long)rA * SEQ + bA * 8;
  const u16* vSrcB = Vp + (long)rB * SEQ + bB * 8;
  u16* kDstA = &Ks[(wv * 64 + lane) * 8];
  u16* kDstB = &Ks[(256 + wv * 64 + lane) * 8];
  u16* vDstA = &Vs[(wv * 64 + lane) * 8];
  u16* vDstB = &Vs[(256 + wv * 64 + lane) * 8];

  int e = l16 & 7;
  int off0 = (q ^ e) * 8;
  int off1 = ((4 + q) ^ e) * 8;

  bf16x8 ones;
#pragma unroll
  for (int j = 0; j < 8; j++) ones[j] = (bf16_t)1.0f;

#pragma unroll
  for (int ph = 0; ph < 2; ph++) {
    int t = ph ? (31 - i) : i;
    int qbase = t * 64 + wv * 16;
    const u16* Qp = Q + (long)(b * SEQ + qbase) * DIM + h * HD;
    bf16x8 aq0 = *(const bf16x8*)&Qp[l16 * DIM + q * 8];
    bf16x8 aq1 = *(const bf16x8*)&Qp[l16 * DIM + 32 + q * 8];
    f32x4 o_acc[4] = {};
    f32x4 l_acc = {};
    int qrow = qbase + l16;

    for (int kt = 0; kt <= t; kt++) {
      long kk = (long)kt * 64;
      __syncthreads();
      gload_lds16(kSrcA + kk * KVDIM, kDstA);
      gload_lds16(kSrcB + kk * KVDIM, kDstB);
      gload_lds16(vSrcA + kk, vDstA);
      gload_lds16(vSrcB + kk, vDstB);
      __syncthreads();

      f32x4 sc[4];
#pragma unroll
      for (int ni = 0; ni < 4; ni++) {
        bf16x8 bk0 = *(const bf16x8*)&Ks[(ni * 16 + l16) * 64 + off0];
        bf16x8 bk1 = *(const bf16x8*)&Ks[(ni * 16 + l16) * 64 + off1];
        f32x4 z = {};
        z = __builtin_amdgcn_mfma_f32_16x16x32_bf16(bk0, aq0, z, 0, 0, 0);
        z = __builtin_amdgcn_mfma_f32_16x16x32_bf16(bk1, aq1, z, 0, 0, 0);
        sc[ni] = z;
      }
      if (kt == t) {
#pragma unroll
        for (int ni = 0; ni < 4; ni++)
#pragma unroll
          for (int r = 0; r < 4; r++) {
            int kv = (int)kk + ni * 16 + q * 4 + r;
            float p = __expf(sc[ni][r]);
            sc[ni][r] = (kv <= qrow) ? p : 0.f;
          }
      } else {
#pragma unroll
        for (int ni = 0; ni < 4; ni++)
#pragma unroll
          for (int r = 0; r < 4; r++) sc[ni][r] = __expf(sc[ni][r]);
      }
#pragma unroll
      for (int ni = 0; ni < 4; ni++) {
        uint2 w;
        w.x = pkbf2(sc[ni][0], sc[ni][1]);
        w.y = pkbf2(sc[ni][2], sc[ni][3]);
        int pblk = (2 * ni + (q >> 1)) ^ e;
        *(uint2*)&Ps[wv][l16 * 64 + pblk * 8 + (q & 1) * 4] = w;
      }
      bf16x8 ap0 = *(const bf16x8*)&Ps[wv][l16 * 64 + off0];
      bf16x8 ap1 = *(const bf16x8*)&Ps[wv][l16 * 64 + off1];
      l_acc = __builtin_amdgcn_mfma_f32_16x16x32_bf16(ap0, ones, l_acc, 0, 0, 0);
      l_acc = __builtin_amdgcn_mfma_f32_16x16x32_bf16(ap1, ones, l_acc, 0, 0, 0);
#pragma unroll
      for (int di = 0; di < 4; di++) {
        bf16x8 bv0 = *(const bf16x8*)&Vs[(di * 16 + l16) * 64 + off0];
        bf16x8 bv1 = *(const bf16x8*)&Vs[(di * 16 + l16) * 64 + off1];
        o_acc[di] = __builtin_amdgcn_mfma_f32_16x16x32_bf16(ap0, bv0, o_acc[di], 0, 0, 0);
        o_acc[di] = __builtin_amdgcn_mfma_f32_16x16x32_bf16(ap1, bv1, o_acc[di], 0, 0, 0);
      }
    }
    long obase = (long)(b * SEQ + qbase + q * 4) * DIM + h * HD;
#pragma unroll
    for (int r = 0; r < 4; r++) {
      float inv = 1.0f / l_acc[r];
#pragma unroll
      for (int di = 0; di < 4; di++)
        AO[obase + (long)r * DIM + di * 16 + l16] = f2b(o_acc[di][r] * inv);
    }
  }
}

extern "C" void kernel_launch(void* const* d_in, const int* in_sizes, int n_in,
                              void* d_out, int out_size, void* d_ws, size_t ws_size,
                              hipStream_t stream) {
  const void* x    = d_in[0];
  const void* Wq   = d_in[1];
  const void* Wk   = d_in[2];
  const void* Wv   = d_in[3];
  const void* Wo   = d_in[4];
  const void* cosb = d_in[5];
  const void* sinb = d_in[6];
  const u32*  probe = (const u32*)d_in[7];

  // workspace: WqkvT 12M + WoT 8M + Qb 16M + Kb 4M + Vt 4M (=44M) + xb 16M opt
  u16* WqkvT = (u16*)d_ws;
  u16* WoT = WqkvT + (size_t)NQKV * DIM;
  u16* Qb  = WoT + (size_t)DIM * DIM;
  u16* Kb  = Qb  + (size_t)BATCH * SEQ * DIM;
  u16* Vt  = Kb  + (size_t)BATCH * SEQ * KVDIM;
  u16* xb  = Vt  + (size_t)BATCH * NKVH * HD * SEQ;
  u16* AO  = Qb;   // alias: each attn wave reads its own Q rows before writing them

  size_t need_xb = ((size_t)(xb - WqkvT) + (size_t)BATCH * SEQ * DIM) * sizeof(u16);
  int use_xb = ws_size >= need_xb;

  dim3 blk32(32, 8);
  transpose_qkv<<<dim3(96, 64), blk32, 0, stream>>>(Wq, Wk, Wv, WqkvT, probe);
  transpose_w<<<dim3(DIM / 32, DIM / 32), blk32, 0, stream>>>(Wo, WoT, DIM, DIM, probe);

  int M = BATCH * SEQ;  // 4096
  if (use_xb) {
    cast_x<<<(M * DIM) / (256 * 8), 256, 0, stream>>>(x, xb, probe);
    gemm_qkv8<<<dim3(NQKV / 256, M / 256), 512, 0, stream>>>(x, xb, WqkvT, Qb, Kb, Vt, probe);
  } else {
    gemm_qkv<<<dim3(NQKV / 128, M / 128), 256, 0, stream>>>(x, WqkvT, Qb, Kb, Vt, 0, probe);
  }

  long rope_slots = (long)M * NH * 32 + (long)M * NKVH * 32;
  rope_both<<<(int)(rope_slots / 256), 256, 0, stream>>>(Qb, Kb, cosb, sinb, probe);

  attn_kernel<<<dim3(16, BATCH * NH), 256, 0, stream>>>(Qb, Kb, Vt, AO);

  gemm_ao8<<<dim3(DIM / 256, M / 128), 512, 0, stream>>>(AO, WoT, d_out, probe);
}

// Round 2
// 340.933 us; speedup vs baseline: 1.0084x; 1.0084x over previous
//
#include <hip/hip_runtime.h>
#include <hip/hip_bf16.h>

typedef unsigned short u16;
typedef unsigned int   u32;
typedef __bf16 bf16_t;
typedef bf16_t bf16x8 __attribute__((ext_vector_type(8)));
typedef u16    u16x8  __attribute__((ext_vector_type(8)));
typedef float  f32x4  __attribute__((ext_vector_type(4)));

#define DIM  2048
#define SEQ  2048
#define BATCH 2
#define NH   32
#define NKVH 8
#define HD   64
#define KVDIM (NKVH*HD)   // 512
#define NQKV (DIM + 2*KVDIM)  // 3072
#define SCALE 0.125f

__device__ __forceinline__ float b2f(u16 u) {
  union { u32 i; float f; } v; v.i = ((u32)u) << 16; return v.f;
}
__device__ __forceinline__ u16 f2b(float f) {
  union { float f; u32 i; } v; v.f = f;
  u32 x = v.i;
  return (u16)((x + 0x7fffu + ((x >> 16) & 1u)) >> 16);  // RNE
}
__device__ __forceinline__ u32 pkbf2(float a, float b) {  // low=a, high=b
  __hip_bfloat162 h = __float22bfloat162_rn(float2{a, b});
  union { __hip_bfloat162 h; u32 u; } v; v.h = h; return v.u;
}
__device__ __forceinline__ int probe_bf16(const u32* probe) { return probe[0] != 0u; }
__device__ __forceinline__ float ext_ld(const void* p, long idx, int mode_bf16) {
  return mode_bf16 ? b2f(((const u16*)p)[idx]) : ((const float*)p)[idx];
}
__device__ __forceinline__ void gload_lds16(const u16* g, u16* l) {
  __builtin_amdgcn_global_load_lds((const __attribute__((address_space(1))) void*)g,
                                   (__attribute__((address_space(3))) void*)l, 16, 0, 0);
}

// ---------------- cast x (ext dtype) -> bf16, 8 elems/thread
__global__ void cast_x(const void* __restrict__ in, u16* __restrict__ out,
                       const u32* __restrict__ probe) {
  int mode = probe_bf16(probe);
  if (mode) return;
  long base = ((long)blockIdx.x * 256 + threadIdx.x) * 8;
  float4 f0 = *(const float4*)((const float*)in + base);
  float4 f1 = *(const float4*)((const float*)in + base + 4);
  u16x8 t;
  t[0] = f2b(f0.x); t[1] = f2b(f0.y); t[2] = f2b(f0.z); t[3] = f2b(f0.w);
  t[4] = f2b(f1.x); t[5] = f2b(f1.y); t[6] = f2b(f1.z); t[7] = f2b(f1.w);
  *(u16x8*)&out[base] = t;
}

// ---------------- fused Wq/Wk/Wv transpose into WqkvT[3072][2048]
__global__ void transpose_qkv(const void* __restrict__ Wq, const void* __restrict__ Wk,
                              const void* __restrict__ Wv, u16* __restrict__ out,
                              const u32* __restrict__ probe) {
  int mode = probe_bf16(probe);
  __shared__ u16 t[32][33];
  int xt = blockIdx.x;
  const void* in; int C, c0, obase;
  if (xt < 64)      { in = Wq; C = DIM;   c0 = xt * 32;        obase = 0; }
  else if (xt < 80) { in = Wk; C = KVDIM; c0 = (xt - 64) * 32; obase = DIM; }
  else              { in = Wv; C = KVDIM; c0 = (xt - 80) * 32; obase = DIM + KVDIM; }
  int r0 = blockIdx.y * 32;
  int tx = threadIdx.x, ty = threadIdx.y;   // (32,8)
#pragma unroll
  for (int i = 0; i < 32; i += 8)
    t[ty + i][tx] = mode ? ((const u16*)in)[(long)(r0 + ty + i) * C + c0 + tx]
                         : f2b(((const float*)in)[(long)(r0 + ty + i) * C + c0 + tx]);
  __syncthreads();
#pragma unroll
  for (int i = 0; i < 32; i += 8)
    out[(long)(obase + c0 + ty + i) * DIM + r0 + tx] = t[tx][ty + i];
}

// ---------------- Wo transpose
__global__ void transpose_w(const void* __restrict__ in, u16* __restrict__ out,
                            int R, int C, const u32* __restrict__ probe) {
  int mode = probe_bf16(probe);
  __shared__ u16 t[32][33];
  int c0 = blockIdx.x * 32, r0 = blockIdx.y * 32;
  int tx = threadIdx.x, ty = threadIdx.y;
#pragma unroll
  for (int i = 0; i < 32; i += 8)
    t[ty + i][tx] = mode ? ((const u16*)in)[(long)(r0 + ty + i) * C + c0 + tx]
                         : f2b(((const float*)in)[(long)(r0 + ty + i) * C + c0 + tx]);
  __syncthreads();
#pragma unroll
  for (int i = 0; i < 32; i += 8)
    out[(long)(c0 + ty + i) * R + r0 + tx] = t[tx][ty + i];
}

// ---------------- RoPE on Q and K in one launch; Q additionally scaled by 1/8
__global__ void rope_both(u16* __restrict__ Qb, u16* __restrict__ Kb,
                          const void* __restrict__ cosb, const void* __restrict__ sinb,
                          const u32* __restrict__ probe) {
  int mode = probe_bf16(probe);
  long gid = (long)blockIdx.x * 256 + threadIdx.x;
  const long NQp = (long)BATCH * SEQ * NH * 32;   // Q pair-slots
  u16* base_p; int n_heads; long t; float osc;
  if (gid < NQp) { base_p = Qb; n_heads = NH; t = gid; osc = SCALE; }
  else           { base_p = Kb; n_heads = NKVH; t = gid - NQp; osc = 1.0f; }
  int pair = t & 31;
  long t2 = t >> 5;
  int h = (int)(t2 % n_heads);
  long row = t2 / n_heads;
  int s = (int)(row & (SEQ - 1));
  long base = row * (n_heads * HD) + h * HD + pair;
  float q0 = b2f(base_p[base]), q1 = b2f(base_p[base + 32]);
  float c0 = ext_ld(cosb, (long)s * HD + pair, mode);
  float c1 = ext_ld(cosb, (long)s * HD + pair + 32, mode);
  float s0 = ext_ld(sinb, (long)s * HD + pair, mode);
  float s1 = ext_ld(sinb, (long)s * HD + pair + 32, mode);
  base_p[base]      = f2b((q0 * c0 - q1 * s0) * osc);
  base_p[base + 32] = f2b((q1 * c1 + q0 * s1) * osc);
}

// =====================================================================
// 8-phase counted-vmcnt GEMM core — m201-template-exact schedule.
// BN=256, BK=64, K=2048, 8 waves (2M x 4N). Double-buffered K-tiles
// (buf0=even tile, buf1=odd tile; all LDS addressing static).
// Per phase: {ds_reads for THIS phase's MFMA; stage 1 unit; barrier;
// lgkmcnt(0); setprio(1); MFMA quadrant; setprio(0); barrier}.
// vmcnt ONLY at phases 4 and 8 (before their barrier): all but newest
// 3 units landed => next tile fully resident. No sched_barrier pinning.
// Stage slots per iter i (tiles e=2i, o=2i+1):
//   ph1: A2(o)->b1   ph2: A1(e+2)->b0  ph3: B1(e+2)->b0  ph4: B2(e+2)->b0
//   ph5: A2(e+2)->b0 ph6: A1(o+2)->b1  ph7: B1(o+2)->b1  ph8: B2(o+2)->b1
// WAR: each stage target's previous reads published by an earlier
// phase's closing barrier (slot-by-slot verified). Phases 4/8 keep only
// the publication barrier (no reads => no closing barrier needed).
// =====================================================================

#define WAITV(N) asm volatile("s_waitcnt vmcnt(%0)" :: "n"(N) : "memory")
#define WAITL()  asm volatile("s_waitcnt lgkmcnt(0)" ::: "memory")
#define BARR()   __builtin_amdgcn_s_barrier()
#define PRIO1()  __builtin_amdgcn_s_setprio(1)
#define PRIO0()  __builtin_amdgcn_s_setprio(0)

#define STAGE_A(h, bufi, kt) do { _Pragma("unroll") \
  for (int _j = 0; _j < AL; ++_j) \
    gload_lds16(Ax + aSrcOff[h][_j] + (kt) * 64, (u16*)&As[(bufi) * (BM * 64) + aDst[h][_j]]); } while (0)

#define STAGE_B(h, bufi, kt) do { _Pragma("unroll") \
  for (int _j = 0; _j < 2; ++_j) \
    gload_lds16(Bt + bSrcOff[h][_j] + (kt) * 64, (u16*)&Bs[(bufi) * (256 * 64) + bDst[h][_j]]); } while (0)

#define LDA_HALF(Lp, mh) do { _Pragma("unroll") \
  for (int _m = 0; _m < MH2; ++_m) { \
    const u16* _r = (Lp) + (wm * WM + (mh) * (WM / 2) + _m * 16 + l16) * 64; \
    af[_m][0] = *(const bf16x8*)&_r[sw0]; \
    af[_m][1] = *(const bf16x8*)&_r[sw1]; } } while (0)

#define LDB_HALF(Lp, nh) do { _Pragma("unroll") \
  for (int _n = 0; _n < 2; ++_n) { \
    const u16* _r = (Lp) + (wn * 64 + (nh) * 32 + _n * 16 + l16) * 64; \
    bfr[nh][_n][0] = *(const bf16x8*)&_r[sw0]; \
    bfr[nh][_n][1] = *(const bf16x8*)&_r[sw1]; } } while (0)

#define MFMA_Q(mh, nh) do { _Pragma("unroll") \
  for (int _m = 0; _m < MH2; ++_m) \
    _Pragma("unroll") \
    for (int _n = 0; _n < 2; ++_n) { \
      f32x4 _z = acc[(mh) * MH2 + _m][(nh) * 2 + _n]; \
      _z = __builtin_amdgcn_mfma_f32_16x16x32_bf16(af[_m][0], bfr[nh][_n][0], _z, 0, 0, 0); \
      _z = __builtin_amdgcn_mfma_f32_16x16x32_bf16(af[_m][1], bfr[nh][_n][1], _z, 0, 0, 0); \
      acc[(mh) * MH2 + _m][(nh) * 2 + _n] = _z; } } while (0)

#define VMS() do { if constexpr (BM == 256) WAITV(6); else WAITV(5); } while (0)

template<int BM, int EPI>
__device__ __forceinline__ void gemm8_core(const u16* __restrict__ Ax, const u16* __restrict__ Bt,
                                           u16* __restrict__ Qb, u16* __restrict__ Kb,
                                           u16* __restrict__ Vt, void* __restrict__ Cout,
                                           const u32* __restrict__ probe) {
  constexpr int WM  = BM / 2;       // wave M extent (128 or 64)
  constexpr int MI  = WM / 16;      // m-frags per wave (8 or 4)
  constexpr int MH2 = MI / 2;       // m-frags per quadrant
  constexpr int AL  = BM / 128;     // A loads per unit per thread (2 or 1)
  constexpr int K = DIM;
  __shared__ __align__(16) u16 As[2 * BM * 64];
  __shared__ __align__(16) u16 Bs[2 * 256 * 64];

  int tid = threadIdx.x, lane = tid & 63, wv = tid >> 6;
  int l16 = lane & 15, q = lane >> 4;
  int wm = wv >> 2, wn = wv & 3;
  int bm0 = blockIdx.y * BM, bn0 = blockIdx.x * 256;

  // staging: lane writes 16B at linear LDS dest; source column pre-swizzled
  // so LDS(row, physblk) holds logical block physblk ^ (row&7).
  int srow = lane >> 3;
  int scolb = ((lane & 7) ^ srow) * 8;
  int e7 = l16 & 7;
  int sw0 = (q ^ e7) * 8, sw1 = ((4 + q) ^ e7) * 8;   // read swizzle, kk=0/1

  int aSrcOff[2][AL], aDst[2][AL];
#pragma unroll
  for (int h = 0; h < 2; ++h)
#pragma unroll
    for (int j = 0; j < AL; ++j) {
      int g = wv * AL + j;
      int rb = (BM == 256) ? ((g >> 3) * 128 + h * 64 + (g & 7) * 8)
                           : ((g >> 2) * 64 + h * 32 + (g & 3) * 8);
      aSrcOff[h][j] = (bm0 + rb + srow) * K + scolb;
      aDst[h][j] = rb * 64 + lane * 8;
    }
  int bSrcOff[2][2], bDst[2][2];
#pragma unroll
  for (int h = 0; h < 2; ++h)
#pragma unroll
    for (int j = 0; j < 2; ++j) {
      int g = wv * 2 + j;
      int rb = (g >> 2) * 64 + h * 32 + (g & 3) * 8;
      bSrcOff[h][j] = (bn0 + rb + srow) * K + scolb;
      bDst[h][j] = rb * 64 + lane * 8;
    }

  const u16* As0 = As;  const u16* As1 = As + BM * 64;
  const u16* Bs0 = Bs;  const u16* Bs1 = Bs + 256 * 64;

  f32x4 acc[MI][4] = {};
  bf16x8 af[MH2][2];
  bf16x8 bfr[2][2][2];

  // prologue: tile0 (4 units) -> buf0, tile1 first 3 units -> buf1;
  // wait all-but-newest-3-units => tile0 resident; publish.
  STAGE_A(0, 0, 0);
  STAGE_B(0, 0, 0);
  STAGE_B(1, 0, 0);
  STAGE_A(1, 0, 0);
  STAGE_A(0, 1, 1);
  STAGE_B(0, 1, 1);
  STAGE_B(1, 1, 1);
  VMS(); BARR();

#pragma unroll 1
  for (int i = 0; i < 16; ++i) {
    int t1 = 2 * i + 1;
    int te = 2 * i + 2; if (te > 31) te = 31;
    int to = 2 * i + 3; if (to > 31) to = 31;
    // ---- ph1: quadrant (0,0) of even tile
    LDA_HALF(As0, 0); LDB_HALF(Bs0, 0);
    STAGE_A(1, 1, t1);
    BARR(); WAITL();
    PRIO1(); MFMA_Q(0, 0); PRIO0(); BARR();
    // ---- ph2: quadrant (0,1)
    LDB_HALF(Bs0, 1);
    STAGE_A(0, 0, te);
    BARR(); WAITL();
    PRIO1(); MFMA_Q(0, 1); PRIO0(); BARR();
    // ---- ph3: quadrant (1,0)
    LDA_HALF(As0, 1);
    STAGE_B(0, 0, te);
    BARR(); WAITL();
    PRIO1(); MFMA_Q(1, 0); PRIO0(); BARR();
    // ---- ph4: quadrant (1,1); vmcnt gate publishes odd tile
    STAGE_B(1, 0, te);
    VMS(); BARR();
    PRIO1(); MFMA_Q(1, 1); PRIO0();
    // ---- ph5: quadrant (0,0) of odd tile
    LDA_HALF(As1, 0); LDB_HALF(Bs1, 0);
    STAGE_A(1, 0, te);
    BARR(); WAITL();
    PRIO1(); MFMA_Q(0, 0); PRIO0(); BARR();
    // ---- ph6: quadrant (0,1)
    LDB_HALF(Bs1, 1);
    STAGE_A(0, 1, to);
    BARR(); WAITL();
    PRIO1(); MFMA_Q(0, 1); PRIO0(); BARR();
    // ---- ph7: quadrant (1,0)
    LDA_HALF(As1, 1);
    STAGE_B(0, 1, to);
    BARR(); WAITL();
    PRIO1(); MFMA_Q(1, 0); PRIO0(); BARR();
    // ---- ph8: quadrant (1,1); vmcnt gate publishes next even tile
    STAGE_B(1, 1, to);
    VMS(); BARR();
    PRIO1(); MFMA_Q(1, 1); PRIO0();
  }
  WAITV(0);   // no LDS-DMA in flight at wave exit

  // ---------------- epilogue
  if constexpr (EPI == 0) {   // fused QKV: split Q / K / V(transposed)
    if (bn0 < DIM) {
#pragma unroll
      for (int mi = 0; mi < MI; ++mi)
#pragma unroll
        for (int ni = 0; ni < 4; ++ni)
#pragma unroll
          for (int r = 0; r < 4; ++r) {
            int m = bm0 + wm * WM + mi * 16 + q * 4 + r;
            int n = bn0 + wn * 64 + ni * 16 + l16;
            Qb[(long)m * DIM + n] = f2b(acc[mi][ni][r]);
          }
    } else if (bn0 < DIM + KVDIM) {
#pragma unroll
      for (int mi = 0; mi < MI; ++mi)
#pragma unroll
        for (int ni = 0; ni < 4; ++ni)
#pragma unroll
          for (int r = 0; r < 4; ++r) {
            int m = bm0 + wm * WM + mi * 16 + q * 4 + r;
            int n = bn0 - DIM + wn * 64 + ni * 16 + l16;
            Kb[(long)m * KVDIM + n] = f2b(acc[mi][ni][r]);
          }
    } else {
#pragma unroll
      for (int mi = 0; mi < MI; ++mi)
#pragma unroll
        for (int ni = 0; ni < 4; ++ni) {
          int vcol = bn0 - (DIM + KVDIM) + wn * 64 + ni * 16 + l16;
          int kvh2 = vcol >> 6, d = vcol & 63;
          int m0 = bm0 + wm * WM + mi * 16 + q * 4;
          int bb = m0 >> 11, s = m0 & (SEQ - 1);
          uint2 w;
          w.x = pkbf2(acc[mi][ni][0], acc[mi][ni][1]);
          w.y = pkbf2(acc[mi][ni][2], acc[mi][ni][3]);
          *(uint2*)&Vt[((long)(bb * NKVH + kvh2) * HD + d) * SEQ + s] = w;
        }
    }
  } else {                    // output projection -> ext dtype
    int mode = probe_bf16(probe);
#pragma unroll
    for (int mi = 0; mi < MI; ++mi)
#pragma unroll
      for (int ni = 0; ni < 4; ++ni)
#pragma unroll
        for (int r = 0; r < 4; ++r) {
          int m = bm0 + wm * WM + mi * 16 + q * 4 + r;
          int n = bn0 + wn * 64 + ni * 16 + l16;
          long idx = (long)m * DIM + n;
          if (mode) ((u16*)Cout)[idx] = f2b(acc[mi][ni][r]);
          else      ((float*)Cout)[idx] = acc[mi][ni][r];
        }
  }
}

__global__ __launch_bounds__(512, 2)
void gemm_qkv8(const void* __restrict__ x, const u16* __restrict__ xb,
               const u16* __restrict__ Bt, u16* __restrict__ Qb, u16* __restrict__ Kb,
               u16* __restrict__ Vt, const u32* __restrict__ probe) {
  const u16* Ax = probe_bf16(probe) ? (const u16*)x : xb;
  gemm8_core<256, 0>(Ax, Bt, Qb, Kb, Vt, nullptr, probe);
}

__global__ __launch_bounds__(512, 2)
void gemm_ao8(const u16* __restrict__ A, const u16* __restrict__ Bt,
              void* __restrict__ C, const u32* __restrict__ probe) {
  gemm8_core<128, 1>(A, Bt, nullptr, nullptr, nullptr, C, probe);
}

// ======== fallback 128x128 fused QKV GEMM (fp32 input without xb room) ========
__launch_bounds__(256)
__global__ void gemm_qkv(const void* __restrict__ A, const u16* __restrict__ Bt,
                         u16* __restrict__ Qb, u16* __restrict__ Kb, u16* __restrict__ Vt,
                         int a_half, const u32* __restrict__ probe) {
  int mode = a_half || probe_bf16(probe);
  __shared__ __align__(16) u16 As[128 * 32];
  __shared__ __align__(16) u16 Bs[128 * 32];
  int tid = threadIdx.x, lane = tid & 63, wv = tid >> 6;
  int l16 = lane & 15, q = lane >> 4;
  int bm0 = blockIdx.y * 128, bn0 = blockIdx.x * 128;
  int mbase = (wv & 1) * 64, nbase = (wv >> 1) * 64;
  int c0 = tid, c1 = tid + 256;
  int r0 = c0 >> 2, s0 = (c0 & 3) ^ ((r0 >> 1) & 3);
  int r1 = c1 >> 2, s1 = (c1 & 3) ^ ((r1 >> 1) & 3);
  const int K = DIM;
  long aoff0 = (long)(bm0 + r0) * K + s0 * 8;
  long aoff1 = (long)(bm0 + r1) * K + s1 * 8;
  long boff0 = (long)(bn0 + r0) * K + s0 * 8;
  long boff1 = (long)(bn0 + r1) * K + s1 * 8;
  int rsw = (q ^ ((l16 >> 1) & 3)) * 8;
  f32x4 acc[4][4] = {};
  for (int k0 = 0; k0 < K; k0 += 32) {
    __syncthreads();
    if (mode) {
      gload_lds16((const u16*)A + aoff0 + k0, &As[wv * 512]);
      gload_lds16((const u16*)A + aoff1 + k0, &As[2048 + wv * 512]);
    } else {
      const float* Af = (const float*)A;
      float4 f0 = *(const float4*)(Af + aoff0 + k0);
      float4 f1 = *(const float4*)(Af + aoff0 + k0 + 4);
      u16x8 t;
      t[0] = f2b(f0.x); t[1] = f2b(f0.y); t[2] = f2b(f0.z); t[3] = f2b(f0.w);
      t[4] = f2b(f1.x); t[5] = f2b(f1.y); t[6] = f2b(f1.z); t[7] = f2b(f1.w);
      *(u16x8*)&As[c0 * 8] = t;
      float4 g0 = *(const float4*)(Af + aoff1 + k0);
      float4 g1 = *(const float4*)(Af + aoff1 + k0 + 4);
      u16x8 u;
      u[0] = f2b(g0.x); u[1] = f2b(g0.y); u[2] = f2b(g0.z); u[3] = f2b(g0.w);
      u[4] = f2b(g1.x); u[5] = f2b(g1.y); u[6] = f2b(g1.z); u[7] = f2b(g1.w);
      *(u16x8*)&As[c1 * 8] = u;
    }
    gload_lds16(Bt + boff0 + k0, &Bs[wv * 512]);
    gload_lds16(Bt + boff1 + k0, &Bs[2048 + wv * 512]);
    __syncthreads();
    bf16x8 af[4], bfr[4];
#pragma unroll
    for (int mi = 0; mi < 4; mi++)
      af[mi] = *(const bf16x8*)&As[(mbase + mi * 16 + l16) * 32 + rsw];
#pragma unroll
    for (int ni = 0; ni < 4; ni++)
      bfr[ni] = *(const bf16x8*)&Bs[(nbase + ni * 16 + l16) * 32 + rsw];
#pragma unroll
    for (int mi = 0; mi < 4; mi++)
#pragma unroll
      for (int ni = 0; ni < 4; ni++)
        acc[mi][ni] = __builtin_amdgcn_mfma_f32_16x16x32_bf16(
            af[mi], bfr[ni], acc[mi][ni], 0, 0, 0);
  }
  if (bn0 < DIM + KVDIM) {   // Q or K block
    u16* Cb; int ldc, ncol0;
    if (bn0 < DIM) { Cb = Qb; ldc = DIM; ncol0 = bn0; }
    else           { Cb = Kb; ldc = KVDIM; ncol0 = bn0 - DIM; }
#pragma unroll
    for (int mi = 0; mi < 4; mi++)
#pragma unroll
      for (int ni = 0; ni < 4; ni++)
#pragma unroll
        for (int r = 0; r < 4; r++) {
          int m = bm0 + mbase + mi * 16 + q * 4 + r;
          int n = ncol0 + nbase + ni * 16 + l16;
          Cb[(long)m * ldc + n] = f2b(acc[mi][ni][r]);
        }
  } else {                   // V block: transposed into Vt(B,KVH,64,S)
    int vcol0 = bn0 - DIM - KVDIM;
#pragma unroll
    for (int mi = 0; mi < 4; mi++)
#pragma unroll
      for (int ni = 0; ni < 4; ni++) {
        int vcol = vcol0 + nbase + ni * 16 + l16;
        int kvh2 = vcol >> 6, d = vcol & 63;
        int m = bm0 + mbase + mi * 16 + q * 4;
        int bb = m >> 11, s = m & (SEQ - 1);
        uint2 w;
        w.x = pkbf2(acc[mi][ni][0], acc[mi][ni][1]);
        w.y = pkbf2(acc[mi][ni][2], acc[mi][ni][3]);
        *(uint2*)&Vt[((long)(bb * NKVH + kvh2) * HD + d) * SEQ + s] = w;
      }
  }
}

// ---------------- fused causal attention: LDS-staged K/V, S^T, fixed-m softmax
__launch_bounds__(256, 4)
__global__ void attn_kernel(const u16* __restrict__ Q, const u16* __restrict__ K,
                            const u16* __restrict__ Vt, u16* __restrict__ AO) {
  __shared__ __align__(16) u16 Ks[64 * 64];      // [kv][d] swizzled, 8 KB
  __shared__ __align__(16) u16 Vs[64 * 64];      // [d][kv] swizzled, 8 KB
  __shared__ __align__(16) u16 Ps[4][16 * 64];   // per-wave P, swizzled, 8 KB
  int tid = threadIdx.x, lane = tid & 63, wv = tid >> 6;
  int l16 = lane & 15, q = lane >> 4;
  int i = blockIdx.x;
  int bh = blockIdx.y;
  int b = bh >> 5, h = bh & 31, kvh = h >> 2;
  const u16* Kp = K + (long)b * SEQ * KVDIM + kvh * HD;
  const u16* Vp = Vt + (long)(b * NKVH + kvh) * HD * SEQ;

  int cA = tid, cB = tid + 256;
  int rA = cA >> 3, bA = (cA & 7) ^ (rA & 7);
  int rB = cB >> 3, bB = (cB & 7) ^ (rB & 7);
  const u16* kSrcA = Kp + (long)rA * KVDIM + bA * 8;
  const u16* kSrcB = Kp + (long)rB * KVDIM + bB * 8;
  const u16* vSrcA = Vp + (long)rA * SEQ + bA * 8;
  const u16* vSrcB = Vp + (long)rB * SEQ + bB * 8;
  u16* kDstA = &Ks[(wv * 64 + lane) * 8];
  u16* kDstB = &Ks[(256 + wv * 64 + lane) * 8];
  u16* vDstA = &Vs[(wv * 64 + lane) * 8];
  u16* vDstB = &Vs[(256 + wv * 64 + lane) * 8];

  int e = l16 & 7;
  int off0 = (q ^ e) * 8;
  int off1 = ((4 + q) ^ e) * 8;

  bf16x8 ones;
#pragma unroll
  for (int j = 0; j < 8; j++) ones[j] = (bf16_t)1.0f;

#pragma unroll
  for (int ph = 0; ph < 2; ph++) {
    int t = ph ? (31 - i) : i;
    int qbase = t * 64 + wv * 16;
    const u16* Qp = Q + (long)(b * SEQ + qbase) * DIM + h * HD;
    bf16x8 aq0 = *(const bf16x8*)&Qp[l16 * DIM + q * 8];
    bf16x8 aq1 = *(const bf16x8*)&Qp[l16 * DIM + 32 + q * 8];
    f32x4 o_acc[4] = {};
    f32x4 l_acc = {};
    int qrow = qbase + l16;

    for (int kt = 0; kt <= t; kt++) {
      long kk = (long)kt * 64;
      __syncthreads();
      gload_lds16(kSrcA + kk * KVDIM, kDstA);
      gload_lds16(kSrcB + kk * KVDIM, kDstB);
      gload_lds16(vSrcA + kk, vDstA);
      gload_lds16(vSrcB + kk, vDstB);
      __syncthreads();

      f32x4 sc[4];
#pragma unroll
      for (int ni = 0; ni < 4; ni++) {
        bf16x8 bk0 = *(const bf16x8*)&Ks[(ni * 16 + l16) * 64 + off0];
        bf16x8 bk1 = *(const bf16x8*)&Ks[(ni * 16 + l16) * 64 + off1];
        f32x4 z = {};
        z = __builtin_amdgcn_mfma_f32_16x16x32_bf16(bk0, aq0, z, 0, 0, 0);
        z = __builtin_amdgcn_mfma_f32_16x16x32_bf16(bk1, aq1, z, 0, 0, 0);
        sc[ni] = z;
      }
      if (kt == t) {
#pragma unroll
        for (int ni = 0; ni < 4; ni++)
#pragma unroll
          for (int r = 0; r < 4; r++) {
            int kv = (int)kk + ni * 16 + q * 4 + r;
            float p = __expf(sc[ni][r]);
            sc[ni][r] = (kv <= qrow) ? p : 0.f;
          }
      } else {
#pragma unroll
        for (int ni = 0; ni < 4; ni++)
#pragma unroll
          for (int r = 0; r < 4; r++) sc[ni][r] = __expf(sc[ni][r]);
      }
#pragma unroll
      for (int ni = 0; ni < 4; ni++) {
        uint2 w;
        w.x = pkbf2(sc[ni][0], sc[ni][1]);
        w.y = pkbf2(sc[ni][2], sc[ni][3]);
        int pblk = (2 * ni + (q >> 1)) ^ e;
        *(uint2*)&Ps[wv][l16 * 64 + pblk * 8 + (q & 1) * 4] = w;
      }
      bf16x8 ap0 = *(const bf16x8*)&Ps[wv][l16 * 64 + off0];
      bf16x8 ap1 = *(const bf16x8*)&Ps[wv][l16 * 64 + off1];
      l_acc = __builtin_amdgcn_mfma_f32_16x16x32_bf16(ap0, ones, l_acc, 0, 0, 0);
      l_acc = __builtin_amdgcn_mfma_f32_16x16x32_bf16(ap1, ones, l_acc, 0, 0, 0);
#pragma unroll
      for (int di = 0; di < 4; di++) {
        bf16x8 bv0 = *(const bf16x8*)&Vs[(di * 16 + l16) * 64 + off0];
        bf16x8 bv1 = *(const bf16x8*)&Vs[(di * 16 + l16) * 64 + off1];
        o_acc[di] = __builtin_amdgcn_mfma_f32_16x16x32_bf16(ap0, bv0, o_acc[di], 0, 0, 0);
        o_acc[di] = __builtin_amdgcn_mfma_f32_16x16x32_bf16(ap1, bv1, o_acc[di], 0, 0, 0);
      }
    }
    long obase = (long)(b * SEQ + qbase + q * 4) * DIM + h * HD;
#pragma unroll
    for (int r = 0; r < 4; r++) {
      float inv = 1.0f / l_acc[r];
#pragma unroll
      for (int di = 0; di < 4; di++)
        AO[obase + (long)r * DIM + di * 16 + l16] = f2b(o_acc[di][r] * inv);
    }
  }
}

extern "C" void kernel_launch(void* const* d_in, const int* in_sizes, int n_in,
                              void* d_out, int out_size, void* d_ws, size_t ws_size,
                              hipStream_t stream) {
  const void* x    = d_in[0];
  const void* Wq   = d_in[1];
  const void* Wk   = d_in[2];
  const void* Wv   = d_in[3];
  const void* Wo   = d_in[4];
  const void* cosb = d_in[5];
  const void* sinb = d_in[6];
  const u32*  probe = (const u32*)d_in[7];

  // workspace: WqkvT 12M + WoT 8M + Qb 16M + Kb 4M + Vt 4M (=44M) + xb 16M opt
  u16* WqkvT = (u16*)d_ws;
  u16* WoT = WqkvT + (size_t)NQKV * DIM;
  u16* Qb  = WoT + (size_t)DIM * DIM;
  u16* Kb  = Qb  + (size_t)BATCH * SEQ * DIM;
  u16* Vt  = Kb  + (size_t)BATCH * SEQ * KVDIM;
  u16* xb  = Vt  + (size_t)BATCH * NKVH * HD * SEQ;
  u16* AO  = Qb;   // alias: each attn wave reads its own Q rows before writing them

  size_t need_xb = ((size_t)(xb - WqkvT) + (size_t)BATCH * SEQ * DIM) * sizeof(u16);
  int use_xb = ws_size >= need_xb;

  dim3 blk32(32, 8);
  transpose_qkv<<<dim3(96, 64), blk32, 0, stream>>>(Wq, Wk, Wv, WqkvT, probe);
  transpose_w<<<dim3(DIM / 32, DIM / 32), blk32, 0, stream>>>(Wo, WoT, DIM, DIM, probe);

  int M = BATCH * SEQ;  // 4096
  if (use_xb) {
    cast_x<<<(M * DIM) / (256 * 8), 256, 0, stream>>>(x, xb, probe);
    gemm_qkv8<<<dim3(NQKV / 256, M / 256), 512, 0, stream>>>(x, xb, WqkvT, Qb, Kb, Vt, probe);
  } else {
    gemm_qkv<<<dim3(NQKV / 128, M / 128), 256, 0, stream>>>(x, WqkvT, Qb, Kb, Vt, 0, probe);
  }

  long rope_slots = (long)M * NH * 32 + (long)M * NKVH * 32;
  rope_both<<<(int)(rope_slots / 256), 256, 0, stream>>>(Qb, Kb, cosb, sinb, probe);

  attn_kernel<<<dim3(16, BATCH * NH), 256, 0, stream>>>(Qb, Kb, Vt, AO);

  gemm_ao8<<<dim3(DIM / 256, M / 128), 512, 0, stream>>>(AO, WoT, d_out, probe);
}